// Round 17
// baseline (265.650 us; speedup 1.0000x reference)
//
#include <hip/hip_runtime.h>
#include <math.h>

// x[50000,128] w1[128,64] b1[64] w2[192,16] b2[16] lin_w[48,16] lin_b[16]
// edge_index[2,800000] edge_index2[2,3000000] (int32, row0=src, row1=dst)
//
// R17 = R16 with (a) agg1f restructured to UNIFORM per-thread work: each
// thread does E2-agg, E1-agg, self for its node sequentially (kills the
// E2-only tail; 3x fewer blocks; same-row stores), (b) part2 direct-write:
// hist -> per-bucket global reservation -> direct scatter (no 64KB stage, no
// 1024-scan; LDS 80->12KB; packed word loses the now-unneeded bucket tag).

#define NPB    64
#define CHUNK  16384
#define HCHUNK 16384

typedef unsigned short us8 __attribute__((ext_vector_type(8)));

__device__ inline float b2f(unsigned short u) {
    return __uint_as_float(((unsigned int)u) << 16);
}
// round-to-nearest-even f32 -> bf16 (finite values; matches __float2bfloat16)
__device__ inline unsigned short f2b(float f) {
    unsigned int u = __float_as_uint(f);
    u = (u + 0x7FFFu + ((u >> 16) & 1u)) >> 16;
    return (unsigned short)u;
}

// ---- GEMM1: hwb = bf16(x @ w1), 64 rows/block, 4x4 tile/thread ----
__global__ void __launch_bounds__(256)
k_gemm1(const float* __restrict__ x, const float* __restrict__ w1,
        unsigned short* __restrict__ hwb, int n) {
    __shared__ float ws[128 * 64];   // 32 KB, [k][c]
    __shared__ float xs[64 * 128];   // 32 KB, [r][k]
    int t = threadIdx.x;
    int row0 = blockIdx.x * 64;
    for (int i = t; i < 128 * 16; i += 256)
        ((float4*)ws)[i] = ((const float4*)w1)[i];
    for (int i = t; i < 64 * 32; i += 256) {
        int r = row0 + (i >> 5);
        ((float4*)xs)[i] = (r < n) ? ((const float4*)x)[r * 32 + (i & 31)]
                                   : make_float4(0.f, 0.f, 0.f, 0.f);
    }
    __syncthreads();
    int tr = t >> 4, tc = t & 15;
    float acc[4][4] = {};
    #pragma unroll 4
    for (int k4 = 0; k4 < 32; ++k4) {
        float4 wv0 = *(const float4*)&ws[(k4 * 4 + 0) * 64 + tc * 4];
        float4 wv1 = *(const float4*)&ws[(k4 * 4 + 1) * 64 + tc * 4];
        float4 wv2 = *(const float4*)&ws[(k4 * 4 + 2) * 64 + tc * 4];
        float4 wv3 = *(const float4*)&ws[(k4 * 4 + 3) * 64 + tc * 4];
        #pragma unroll
        for (int r = 0; r < 4; ++r) {
            float4 xv = *(const float4*)&xs[(tr * 4 + r) * 128 + k4 * 4];
            acc[r][0] = fmaf(xv.x, wv0.x, acc[r][0]);
            acc[r][1] = fmaf(xv.x, wv0.y, acc[r][1]);
            acc[r][2] = fmaf(xv.x, wv0.z, acc[r][2]);
            acc[r][3] = fmaf(xv.x, wv0.w, acc[r][3]);
            acc[r][0] = fmaf(xv.y, wv1.x, acc[r][0]);
            acc[r][1] = fmaf(xv.y, wv1.y, acc[r][1]);
            acc[r][2] = fmaf(xv.y, wv1.z, acc[r][2]);
            acc[r][3] = fmaf(xv.y, wv1.w, acc[r][3]);
            acc[r][0] = fmaf(xv.z, wv2.x, acc[r][0]);
            acc[r][1] = fmaf(xv.z, wv2.y, acc[r][1]);
            acc[r][2] = fmaf(xv.z, wv2.z, acc[r][2]);
            acc[r][3] = fmaf(xv.z, wv2.w, acc[r][3]);
            acc[r][0] = fmaf(xv.w, wv3.x, acc[r][0]);
            acc[r][1] = fmaf(xv.w, wv3.y, acc[r][1]);
            acc[r][2] = fmaf(xv.w, wv3.z, acc[r][2]);
            acc[r][3] = fmaf(xv.w, wv3.w, acc[r][3]);
        }
    }
    #pragma unroll
    for (int r = 0; r < 4; ++r) {
        int rr = row0 + tr * 4 + r;
        if (rr < n) {
            ushort4 o;
            o.x = f2b(acc[r][0]); o.y = f2b(acc[r][1]);
            o.z = f2b(acc[r][2]); o.w = f2b(acc[r][3]);
            *(ushort4*)&hwb[rr * 64 + tc * 4] = o;
        }
    }
}

// ------- fused bucket histogram, both edge sets (blockIdx split) -------
__global__ void k_hist2(const int* __restrict__ dstA, int* __restrict__ bhA, int EA, int nbA,
                        const int* __restrict__ dstB, int* __restrict__ bhB, int EB) {
    __shared__ int lh[1024];
    const int* dst; int* bh; int E; int cb;
    if ((int)blockIdx.x < nbA) { dst = dstA; bh = bhA; E = EA; cb = blockIdx.x; }
    else                       { dst = dstB; bh = bhB; E = EB; cb = blockIdx.x - nbA; }
    int t = threadIdx.x;
    for (int i = t; i < 1024; i += 256) lh[i] = 0;
    __syncthreads();
    int base = cb * HCHUNK;
    int cnt = min(HCHUNK, E - base);
    for (int i = t; i < cnt; i += 256) atomicAdd(&lh[dst[base + i] >> 6], 1);
    __syncthreads();
    for (int b = t; b < 1024; b += 256)
        if (lh[b]) atomicAdd(&bh[b], lh[b]);
}

// ------- scan bucket histograms -> bbase (exclusive) and bcur -------
__global__ void k_bscan(const int* __restrict__ bhA, int* __restrict__ bbA, int* __restrict__ bcA,
                        const int* __restrict__ bhB, int* __restrict__ bbB, int* __restrict__ bcB,
                        int B) {
    const int* bh = blockIdx.x ? bhB : bhA;
    int* bb = blockIdx.x ? bbB : bbA;
    int* bc = blockIdx.x ? bcB : bcA;
    int t = threadIdx.x;
    int carry = 0;
    int nch = (B + 63) >> 6;
    for (int c = 0; c < nch; ++c) {
        int idx = c * 64 + t;
        int v = (idx < B) ? bh[idx] : 0;
        int incl = v;
        #pragma unroll
        for (int off = 1; off < 64; off <<= 1) {
            int tv = __shfl_up(incl, off);
            if (t >= off) incl += tv;
        }
        if (idx < B) { bb[idx] = incl - v + carry; bc[idx] = incl - v + carry; }
        carry += __shfl(incl, 63);
    }
    if (t == 0) bb[B] = carry;
}

// ------- direct-write coarse partition (no stage, no scan) -------
// packed word: src(16b) | dstlocal(6b)<<16 (bucket implied by position)
__global__ void __launch_bounds__(1024)
k_part2(const int* __restrict__ srcA, const int* __restrict__ dstA,
        int* __restrict__ bcurA, unsigned int* __restrict__ outA, int EA, int nbA,
        const int* __restrict__ srcB, const int* __restrict__ dstB,
        int* __restrict__ bcurB, unsigned int* __restrict__ outB, int EB) {
    __shared__ int lh[1024];
    __shared__ int gof[1024];
    __shared__ int lcur[1024];
    const int *src, *dst; int *bcur; unsigned int *out; int E, cb;
    if ((int)blockIdx.x < nbA) { src = srcA; dst = dstA; bcur = bcurA; out = outA; E = EA; cb = blockIdx.x; }
    else                       { src = srcB; dst = dstB; bcur = bcurB; out = outB; E = EB; cb = blockIdx.x - nbA; }
    int t = threadIdx.x;
    int base = cb * CHUNK;
    int cnt = min(CHUNK, E - base);
    lh[t] = 0;
    lcur[t] = 0;
    __syncthreads();
    for (int i = t; i < cnt; i += 1024) atomicAdd(&lh[dst[base + i] >> 6], 1);
    __syncthreads();
    gof[t] = lh[t] ? atomicAdd(&bcur[t], lh[t]) : 0;
    __syncthreads();
    for (int i = t; i < cnt; i += 1024) {
        int d = dst[base + i];
        int s = src[base + i];
        int bkt = d >> 6;
        int p = atomicAdd(&lcur[bkt], 1);
        out[gof[bkt] + p] = (unsigned int)s | ((unsigned int)(d & 63) << 16);
    }
}

// ------- fused CSR build: deg count + scan -> rs/dinv, then in-window scatter ----
__global__ void __launch_bounds__(256)
k_csr2(const int* __restrict__ bbaseA, const unsigned int* __restrict__ ebufA,
       int* __restrict__ rsA, float* __restrict__ dvA, unsigned short* __restrict__ ssrcA, int EA,
       const int* __restrict__ bbaseB, const unsigned int* __restrict__ ebufB,
       int* __restrict__ rsB, float* __restrict__ dvB, unsigned short* __restrict__ ssrcB, int EB,
       int B, int n) {
    __shared__ int cnt[64];
    __shared__ int lcur[64];
    const int* bbase; const unsigned int* ebuf; int* rs; float* dv;
    unsigned short* ssrc; int b, Etot;
    if ((int)blockIdx.x < B) { bbase = bbaseA; ebuf = ebufA; rs = rsA; dv = dvA; ssrc = ssrcA; b = blockIdx.x; Etot = EA; }
    else                     { bbase = bbaseB; ebuf = ebufB; rs = rsB; dv = dvB; ssrc = ssrcB; b = blockIdx.x - B; Etot = EB; }
    int t = threadIdx.x;
    if (t < 64) cnt[t] = 0;
    __syncthreads();
    int beg = bbase[b], end = bbase[b + 1];
    for (int i = beg + t; i < end; i += 256)
        atomicAdd(&cnt[(ebuf[i] >> 16) & 63u], 1);
    __syncthreads();
    if (t < 64) {
        int v = cnt[t];
        int incl = v;
        #pragma unroll
        for (int off = 1; off < 64; off <<= 1) {
            int tv = __shfl_up(incl, off);
            if (t >= off) incl += tv;
        }
        int start = beg + incl - v;
        lcur[t] = start;
        int node = b * NPB + t;
        if (node < n) {
            rs[node] = start;
            dv[node] = (v > 0) ? rsqrtf((float)v) : 0.f;
        }
    }
    __syncthreads();
    for (int i = beg + t; i < end; i += 256) {
        unsigned int e = ebuf[i];
        int p = atomicAdd(&lcur[(e >> 16) & 63u], 1);
        ssrc[p] = (unsigned short)(e & 0xFFFFu);
    }
    if (t == 0 && b == B - 1) rs[n] = Etot;
}

// ------- pack: psrc[i] = src | bf16(dinv[src])<<16 (both sets, grid-stride) ----
__global__ void k_pack(const unsigned short* __restrict__ ssrc1, const float* __restrict__ dinv1,
                       unsigned int* __restrict__ p1, int E1,
                       const unsigned short* __restrict__ ssrc2, const float* __restrict__ dinv2,
                       unsigned int* __restrict__ p2, int E2) {
    int stride = gridDim.x * 256;
    for (int i = blockIdx.x * 256 + threadIdx.x; i < E1 + E2; i += stride) {
        if (i < E1) {
            int s = ssrc1[i];
            p1[i] = (unsigned int)s | ((unsigned int)f2b(dinv1[s]) << 16);
        } else {
            int j = i - E1;
            int s = ssrc2[j];
            p2[j] = (unsigned int)s | ((unsigned int)f2b(dinv2[s]) << 16);
        }
    }
}

// ------- x8-unrolled 64-feat gather accumulate (packed stream) -------
__device__ inline void agg64_acc(int beg, int end,
                                 const unsigned int* __restrict__ psrc,
                                 const us8* __restrict__ hwb8, int q,
                                 float* __restrict__ a) {
    #pragma unroll
    for (int j = 0; j < 8; ++j) a[j] = 0.f;
    int i = beg;
    for (; i + 8 <= end; i += 8) {
        unsigned int e0 = psrc[i + 0], e1 = psrc[i + 1], e2 = psrc[i + 2], e3 = psrc[i + 3];
        unsigned int e4 = psrc[i + 4], e5 = psrc[i + 5], e6 = psrc[i + 6], e7 = psrc[i + 7];
        int s0 = e0 & 0xFFFFu, s1 = e1 & 0xFFFFu, s2 = e2 & 0xFFFFu, s3 = e3 & 0xFFFFu;
        int s4 = e4 & 0xFFFFu, s5 = e5 & 0xFFFFu, s6 = e6 & 0xFFFFu, s7 = e7 & 0xFFFFu;
        float c0 = b2f((unsigned short)(e0 >> 16)), c1 = b2f((unsigned short)(e1 >> 16));
        float c2 = b2f((unsigned short)(e2 >> 16)), c3 = b2f((unsigned short)(e3 >> 16));
        float c4 = b2f((unsigned short)(e4 >> 16)), c5 = b2f((unsigned short)(e5 >> 16));
        float c6 = b2f((unsigned short)(e6 >> 16)), c7 = b2f((unsigned short)(e7 >> 16));
        us8 h0 = hwb8[s0 * 8 + q], h1 = hwb8[s1 * 8 + q];
        us8 h2 = hwb8[s2 * 8 + q], h3 = hwb8[s3 * 8 + q];
        us8 h4 = hwb8[s4 * 8 + q], h5 = hwb8[s5 * 8 + q];
        us8 h6 = hwb8[s6 * 8 + q], h7 = hwb8[s7 * 8 + q];
        #pragma unroll
        for (int j = 0; j < 8; ++j) {
            a[j] = fmaf(b2f(h0[j]), c0, a[j]);
            a[j] = fmaf(b2f(h1[j]), c1, a[j]);
            a[j] = fmaf(b2f(h2[j]), c2, a[j]);
            a[j] = fmaf(b2f(h3[j]), c3, a[j]);
            a[j] = fmaf(b2f(h4[j]), c4, a[j]);
            a[j] = fmaf(b2f(h5[j]), c5, a[j]);
            a[j] = fmaf(b2f(h6[j]), c6, a[j]);
            a[j] = fmaf(b2f(h7[j]), c7, a[j]);
        }
    }
    for (; i < end; ++i) {
        unsigned int e = psrc[i];
        int s = e & 0xFFFFu;
        float sc = b2f((unsigned short)(e >> 16));
        us8 h = hwb8[s * 8 + q];
        #pragma unroll
        for (int j = 0; j < 8; ++j) a[j] = fmaf(b2f(h[j]), sc, a[j]);
    }
}

// ------- uniform layer-1: each thread does E2-agg, E1-agg, self for node v ------
__global__ void k_agg1f(const int* __restrict__ rs1, const unsigned int* __restrict__ psrc1,
                        const float* __restrict__ dinv1,
                        const int* __restrict__ rs2, const unsigned int* __restrict__ psrc2,
                        const float* __restrict__ dinv2,
                        const us8* __restrict__ hwb8, const float* __restrict__ b1,
                        unsigned short* __restrict__ R1b, int n) {
    int tid = blockIdx.x * 256 + threadIdx.x;
    int v = tid >> 3, q = tid & 7;
    if (v >= n) return;
    float a[8];
    us8* rowOut = (us8*)&R1b[v * 192];
    // E2 branch -> units [8,16)
    agg64_acc(rs2[v], rs2[v + 1], psrc2, hwb8, q, a);
    float dd2 = dinv2[v];
    us8 o;
    #pragma unroll
    for (int j = 0; j < 8; ++j) {
        float r = fmaf(a[j], dd2, b1[q * 8 + j]);
        o[j] = f2b(r > 0.f ? r : 0.f);
    }
    rowOut[8 + q] = o;
    // E1 branch -> units [0,8)
    agg64_acc(rs1[v], rs1[v + 1], psrc1, hwb8, q, a);
    float dd1 = dinv1[v];
    #pragma unroll
    for (int j = 0; j < 8; ++j) {
        float r = fmaf(a[j], dd1, b1[q * 8 + j]);
        o[j] = f2b(r > 0.f ? r : 0.f);
    }
    rowOut[q] = o;
    // self branch -> units [16,24)
    us8 h = hwb8[v * 8 + q];
    #pragma unroll
    for (int j = 0; j < 8; ++j) {
        float r = b2f(h[j]) + b1[q * 8 + j];
        o[j] = f2b(r > 0.f ? r : 0.f);
    }
    rowOut[16 + q] = o;
}

// ---------------- GEMM2: hwb2 = bf16(R1 @ w2)  ([n,192]@[192,16]) ----------------
__global__ void __launch_bounds__(256)
k_gemm2(const unsigned short* __restrict__ R1b, const float* __restrict__ w2,
        unsigned short* __restrict__ hwb2, int n) {
    __shared__ float ws[192 * 16];
    __shared__ float rs[16][193];
    int t = threadIdx.x;
    for (int i = t; i < 192 * 16; i += 256) ws[i] = w2[i];
    int row0 = blockIdx.x * 16;
    for (int i = t; i < 16 * 192; i += 256) {
        int r = i / 192, j = i - r * 192;
        int v = row0 + r;
        rs[r][j] = (v < n) ? b2f(R1b[v * 192 + j]) : 0.f;
    }
    __syncthreads();
    int r = t >> 4, c = t & 15;
    int v = row0 + r;
    if (v >= n) return;
    float acc = 0.f;
    #pragma unroll 8
    for (int j = 0; j < 192; ++j) acc += rs[r][j] * ws[j * 16 + c];
    hwb2[v * 16 + c] = f2b(acc);
}

// ------- 16-feat gather (2 lanes/node), packed stream, scalar loads -------
__device__ inline void gath16(const int* __restrict__ rs,
                              const unsigned int* __restrict__ psrc,
                              const us8* __restrict__ h8,
                              int v, int q, float* __restrict__ a) {
    int beg = rs[v], end = rs[v + 1];
    #pragma unroll
    for (int j = 0; j < 8; ++j) a[j] = 0.f;
    int i = beg;
    for (; i + 8 <= end; i += 8) {
        unsigned int e0 = psrc[i + 0], e1 = psrc[i + 1], e2 = psrc[i + 2], e3 = psrc[i + 3];
        unsigned int e4 = psrc[i + 4], e5 = psrc[i + 5], e6 = psrc[i + 6], e7 = psrc[i + 7];
        int s0 = e0 & 0xFFFFu, s1 = e1 & 0xFFFFu, s2 = e2 & 0xFFFFu, s3 = e3 & 0xFFFFu;
        int s4 = e4 & 0xFFFFu, s5 = e5 & 0xFFFFu, s6 = e6 & 0xFFFFu, s7 = e7 & 0xFFFFu;
        float c0 = b2f((unsigned short)(e0 >> 16)), c1 = b2f((unsigned short)(e1 >> 16));
        float c2 = b2f((unsigned short)(e2 >> 16)), c3 = b2f((unsigned short)(e3 >> 16));
        float c4 = b2f((unsigned short)(e4 >> 16)), c5 = b2f((unsigned short)(e5 >> 16));
        float c6 = b2f((unsigned short)(e6 >> 16)), c7 = b2f((unsigned short)(e7 >> 16));
        us8 h0 = h8[s0 * 2 + q], h1 = h8[s1 * 2 + q];
        us8 h2 = h8[s2 * 2 + q], h3 = h8[s3 * 2 + q];
        us8 h4 = h8[s4 * 2 + q], h5 = h8[s5 * 2 + q];
        us8 h6 = h8[s6 * 2 + q], h7 = h8[s7 * 2 + q];
        #pragma unroll
        for (int j = 0; j < 8; ++j) {
            a[j] = fmaf(b2f(h0[j]), c0, a[j]);
            a[j] = fmaf(b2f(h1[j]), c1, a[j]);
            a[j] = fmaf(b2f(h2[j]), c2, a[j]);
            a[j] = fmaf(b2f(h3[j]), c3, a[j]);
            a[j] = fmaf(b2f(h4[j]), c4, a[j]);
            a[j] = fmaf(b2f(h5[j]), c5, a[j]);
            a[j] = fmaf(b2f(h6[j]), c6, a[j]);
            a[j] = fmaf(b2f(h7[j]), c7, a[j]);
        }
    }
    for (; i < end; ++i) {
        unsigned int e = psrc[i];
        int s = e & 0xFFFFu;
        float sc = b2f((unsigned short)(e >> 16));
        us8 h = h8[s * 2 + q];
        #pragma unroll
        for (int j = 0; j < 8; ++j) a[j] = fmaf(b2f(h[j]), sc, a[j]);
    }
}

// ------- fused layer-2 aggregate + linear head + log_softmax (128 nodes/block) ----
__global__ void __launch_bounds__(256)
k_l2f(const int* __restrict__ rs1, const unsigned int* __restrict__ psrc1,
      const float* __restrict__ dinv1,
      const int* __restrict__ rs2, const unsigned int* __restrict__ psrc2,
      const float* __restrict__ dinv2,
      const us8* __restrict__ hwb2_8, const unsigned short* __restrict__ hwb2,
      const float* __restrict__ b2, const float* __restrict__ lw,
      const float* __restrict__ lb, float* __restrict__ out, int n) {
    __shared__ float accA[128 * 16];
    __shared__ float accB[128 * 16];
    __shared__ float lws[48 * 16];
    __shared__ float r2s[16][49];
    int t = threadIdx.x;
    int v0 = blockIdx.x * 128;
    for (int i = t; i < 48 * 16; i += 256) lws[i] = lw[i];
    int vl = t >> 1, q = t & 1;
    int v = v0 + vl;
    if (v < n) {
        float a[8];
        gath16(rs2, psrc2, hwb2_8, v, q, a);
        #pragma unroll
        for (int j = 0; j < 8; ++j) accB[vl * 16 + q * 8 + j] = a[j];
        gath16(rs1, psrc1, hwb2_8, v, q, a);
        #pragma unroll
        for (int j = 0; j < 8; ++j) accA[vl * 16 + q * 8 + j] = a[j];
    }
    __syncthreads();
    int ni = t >> 4, c = t & 15;
    for (int p = 0; p < 8; ++p) {
        int vv = v0 + p * 16 + ni;
        int vl2 = p * 16 + ni;
        if (vv < n) {
            float bb = b2[c];
            r2s[ni][c]      = fmaf(dinv1[vv], accA[vl2 * 16 + c], bb);
            r2s[ni][16 + c] = fmaf(dinv2[vv], accB[vl2 * 16 + c], bb);
            r2s[ni][32 + c] = b2f(hwb2[vv * 16 + c]) + bb;
        }
        __syncthreads();
        if (vv < n) {
            float o = lb[c];
            #pragma unroll
            for (int j = 0; j < 48; ++j) o += r2s[ni][j] * lws[j * 16 + c];
            float m = o;
            for (int off = 8; off >= 1; off >>= 1) m = fmaxf(m, __shfl_xor(m, off, 16));
            float e = expf(o - m);
            float ssum = e;
            for (int off = 8; off >= 1; off >>= 1) ssum += __shfl_xor(ssum, off, 16);
            out[vv * 16 + c] = (o - m) - logf(ssum);
        }
        __syncthreads();
    }
}

extern "C" void kernel_launch(void* const* d_in, const int* in_sizes, int n_in,
                              void* d_out, int out_size, void* d_ws, size_t ws_size,
                              hipStream_t stream) {
    const float* x     = (const float*)d_in[0];
    const float* w1    = (const float*)d_in[1];
    const float* b1    = (const float*)d_in[2];
    const float* w2    = (const float*)d_in[3];
    const float* b2    = (const float*)d_in[4];
    const float* lin_w = (const float*)d_in[5];
    const float* lin_b = (const float*)d_in[6];
    const int*   ei    = (const int*)d_in[7];
    const int*   ei2   = (const int*)d_in[8];

    const int n  = in_sizes[0] / 128;   // 50000
    const int E1 = in_sizes[7] / 2;     // 800000
    const int E2 = in_sizes[8] / 2;     // 3000000
    const int B  = (n + NPB - 1) / NPB; // 782

    char* ws = (char*)d_ws;
    unsigned short* hwb   = (unsigned short*)(ws + 0);         // [n,64] bf16 -> 6.4M
    unsigned short* hwb2  = (unsigned short*)(ws + 6400000);   // [n,16] bf16 -> 8.0M
    unsigned short* R1b   = (unsigned short*)(ws + 8000000);   // [n,192] bf16 -> 27.2M
    unsigned short* ssrc1 = (unsigned short*)(ws + 27200000);  // [E1] -> 28.8M
    unsigned short* ssrc2 = (unsigned short*)(ws + 28800000);  // [E2] -> 34.8M
    unsigned int* ebuf1   = (unsigned int*)(ws + 34800000);    // [E1] -> 38.0M (dead after csr2)
    unsigned int* ebuf2   = (unsigned int*)(ws + 38000000);    // [E2] -> 50.0M (dead after csr2)
    unsigned int* psrc1   = ebuf1;                             // packed reuse
    unsigned int* psrc2   = ebuf2;                             // packed reuse
    float*        dinv1   = (float*)(ws + 56800000);           // [n]
    float*        dinv2   = (float*)(ws + 57000000);           // [n]
    int*          rs1     = (int*)(ws + 57200000);             // [n+1]
    int*          rs2     = (int*)(ws + 57400016);             // [n+1]
    int*          bhist1  = (int*)(ws + 58000032);             // [1024]
    int*          bhist2  = (int*)(ws + 58004128);             // [1024] (contiguous)
    int*          bbase1  = (int*)(ws + 58008224);             // [B+1]
    int*          bbase2  = (int*)(ws + 58012320);             // [B+1]
    int*          bcur1   = (int*)(ws + 58016416);             // [1024]
    int*          bcur2   = (int*)(ws + 58020512);             // [1024]

    hipMemsetAsync(bhist1, 0, 8192, stream);   // bhist1+bhist2, contiguous

    k_gemm1<<<(n + 63) / 64, 256, 0, stream>>>(x, w1, hwb, n);

    const int nbh1 = (E1 + HCHUNK - 1) / HCHUNK, nbh2 = (E2 + HCHUNK - 1) / HCHUNK;
    k_hist2<<<nbh1 + nbh2, 256, 0, stream>>>(ei + E1, bhist1, E1, nbh1,
                                             ei2 + E2, bhist2, E2);
    k_bscan<<<2, 64, 0, stream>>>(bhist1, bbase1, bcur1, bhist2, bbase2, bcur2, B);

    const int nbp1 = (E1 + CHUNK - 1) / CHUNK, nbp2 = (E2 + CHUNK - 1) / CHUNK;
    k_part2<<<nbp1 + nbp2, 1024, 0, stream>>>(ei, ei + E1, bcur1, ebuf1, E1, nbp1,
                                              ei2, ei2 + E2, bcur2, ebuf2, E2);

    k_csr2<<<2 * B, 256, 0, stream>>>(bbase1, ebuf1, rs1, dinv1, ssrc1, E1,
                                      bbase2, ebuf2, rs2, dinv2, ssrc2, E2, B, n);

    k_pack<<<2048, 256, 0, stream>>>(ssrc1, dinv1, psrc1, E1, ssrc2, dinv2, psrc2, E2);

    k_agg1f<<<(n * 8 + 255) / 256, 256, 0, stream>>>(rs1, psrc1, dinv1,
                                                     rs2, psrc2, dinv2,
                                                     (const us8*)hwb, b1, R1b, n);

    k_gemm2<<<(n + 15) / 16, 256, 0, stream>>>(R1b, w2, hwb2, n);

    k_l2f<<<(n + 127) / 128, 256, 0, stream>>>(rs1, psrc1, dinv1, rs2, psrc2, dinv2,
                                               (const us8*)hwb2, hwb2, b2,
                                               lin_w, lin_b, (float*)d_out, n);
}

// Round 18
// 235.227 us; speedup vs baseline: 1.1293x; 1.1293x over previous
//
#include <hip/hip_runtime.h>
#include <math.h>

// x[50000,128] w1[128,64] b1[64] w2[192,16] b2[16] lin_w[48,16] lin_b[16]
// edge_index[2,800000] edge_index2[2,3000000] (int32, row0=src, row1=dst)
//
// R18 = R16 verbatim (best proven config: staged part2@1024, segmented agg1f,
// packed psrc, fused l2f) + int4-vectorized dst reads in k_hist2 (streaming
// read, 4x fewer load instrs). R17's direct-write part2 (write-amp returned)
// and uniform agg1f (longer per-thread chains) are both reverted.

#define NPB    64
#define CHUNK  16384
#define HCHUNK 16384

typedef unsigned short us8 __attribute__((ext_vector_type(8)));

__device__ inline float b2f(unsigned short u) {
    return __uint_as_float(((unsigned int)u) << 16);
}
// round-to-nearest-even f32 -> bf16 (finite values; matches __float2bfloat16)
__device__ inline unsigned short f2b(float f) {
    unsigned int u = __float_as_uint(f);
    u = (u + 0x7FFFu + ((u >> 16) & 1u)) >> 16;
    return (unsigned short)u;
}

// ---- GEMM1: hwb = bf16(x @ w1), 64 rows/block, 4x4 tile/thread ----
__global__ void __launch_bounds__(256)
k_gemm1(const float* __restrict__ x, const float* __restrict__ w1,
        unsigned short* __restrict__ hwb, int n) {
    __shared__ float ws[128 * 64];   // 32 KB, [k][c]
    __shared__ float xs[64 * 128];   // 32 KB, [r][k]
    int t = threadIdx.x;
    int row0 = blockIdx.x * 64;
    for (int i = t; i < 128 * 16; i += 256)
        ((float4*)ws)[i] = ((const float4*)w1)[i];
    for (int i = t; i < 64 * 32; i += 256) {
        int r = row0 + (i >> 5);
        ((float4*)xs)[i] = (r < n) ? ((const float4*)x)[r * 32 + (i & 31)]
                                   : make_float4(0.f, 0.f, 0.f, 0.f);
    }
    __syncthreads();
    int tr = t >> 4, tc = t & 15;
    float acc[4][4] = {};
    #pragma unroll 4
    for (int k4 = 0; k4 < 32; ++k4) {
        float4 wv0 = *(const float4*)&ws[(k4 * 4 + 0) * 64 + tc * 4];
        float4 wv1 = *(const float4*)&ws[(k4 * 4 + 1) * 64 + tc * 4];
        float4 wv2 = *(const float4*)&ws[(k4 * 4 + 2) * 64 + tc * 4];
        float4 wv3 = *(const float4*)&ws[(k4 * 4 + 3) * 64 + tc * 4];
        #pragma unroll
        for (int r = 0; r < 4; ++r) {
            float4 xv = *(const float4*)&xs[(tr * 4 + r) * 128 + k4 * 4];
            acc[r][0] = fmaf(xv.x, wv0.x, acc[r][0]);
            acc[r][1] = fmaf(xv.x, wv0.y, acc[r][1]);
            acc[r][2] = fmaf(xv.x, wv0.z, acc[r][2]);
            acc[r][3] = fmaf(xv.x, wv0.w, acc[r][3]);
            acc[r][0] = fmaf(xv.y, wv1.x, acc[r][0]);
            acc[r][1] = fmaf(xv.y, wv1.y, acc[r][1]);
            acc[r][2] = fmaf(xv.y, wv1.z, acc[r][2]);
            acc[r][3] = fmaf(xv.y, wv1.w, acc[r][3]);
            acc[r][0] = fmaf(xv.z, wv2.x, acc[r][0]);
            acc[r][1] = fmaf(xv.z, wv2.y, acc[r][1]);
            acc[r][2] = fmaf(xv.z, wv2.z, acc[r][2]);
            acc[r][3] = fmaf(xv.z, wv2.w, acc[r][3]);
            acc[r][0] = fmaf(xv.w, wv3.x, acc[r][0]);
            acc[r][1] = fmaf(xv.w, wv3.y, acc[r][1]);
            acc[r][2] = fmaf(xv.w, wv3.z, acc[r][2]);
            acc[r][3] = fmaf(xv.w, wv3.w, acc[r][3]);
        }
    }
    #pragma unroll
    for (int r = 0; r < 4; ++r) {
        int rr = row0 + tr * 4 + r;
        if (rr < n) {
            ushort4 o;
            o.x = f2b(acc[r][0]); o.y = f2b(acc[r][1]);
            o.z = f2b(acc[r][2]); o.w = f2b(acc[r][3]);
            *(ushort4*)&hwb[rr * 64 + tc * 4] = o;
        }
    }
}

// ------- fused bucket histogram, both edge sets; int4-vectorized dst reads -------
__global__ void k_hist2(const int* __restrict__ dstA, int* __restrict__ bhA, int EA, int nbA,
                        const int* __restrict__ dstB, int* __restrict__ bhB, int EB) {
    __shared__ int lh[1024];
    const int* dst; int* bh; int E; int cb;
    if ((int)blockIdx.x < nbA) { dst = dstA; bh = bhA; E = EA; cb = blockIdx.x; }
    else                       { dst = dstB; bh = bhB; E = EB; cb = blockIdx.x - nbA; }
    int t = threadIdx.x;
    for (int i = t; i < 1024; i += 256) lh[i] = 0;
    __syncthreads();
    int base = cb * HCHUNK;
    int cnt = min(HCHUNK, E - base);
    int nv = cnt >> 2;
    const int4* d4 = (const int4*)(dst + base);   // base & ptr both 16B-aligned
    for (int i = t; i < nv; i += 256) {
        int4 d = d4[i];
        atomicAdd(&lh[d.x >> 6], 1);
        atomicAdd(&lh[d.y >> 6], 1);
        atomicAdd(&lh[d.z >> 6], 1);
        atomicAdd(&lh[d.w >> 6], 1);
    }
    for (int i = (nv << 2) + t; i < cnt; i += 256)
        atomicAdd(&lh[dst[base + i] >> 6], 1);
    __syncthreads();
    for (int b = t; b < 1024; b += 256)
        if (lh[b]) atomicAdd(&bh[b], lh[b]);
}

// ------- scan bucket histograms -> bbase (exclusive) and bcur -------
__global__ void k_bscan(const int* __restrict__ bhA, int* __restrict__ bbA, int* __restrict__ bcA,
                        const int* __restrict__ bhB, int* __restrict__ bbB, int* __restrict__ bcB,
                        int B) {
    const int* bh = blockIdx.x ? bhB : bhA;
    int* bb = blockIdx.x ? bbB : bbA;
    int* bc = blockIdx.x ? bcB : bcA;
    int t = threadIdx.x;
    int carry = 0;
    int nch = (B + 63) >> 6;
    for (int c = 0; c < nch; ++c) {
        int idx = c * 64 + t;
        int v = (idx < B) ? bh[idx] : 0;
        int incl = v;
        #pragma unroll
        for (int off = 1; off < 64; off <<= 1) {
            int tv = __shfl_up(incl, off);
            if (t >= off) incl += tv;
        }
        if (idx < B) { bb[idx] = incl - v + carry; bc[idx] = incl - v + carry; }
        carry += __shfl(incl, 63);
    }
    if (t == 0) bb[B] = carry;
}

// ------- fused coarse partition, 1024 threads, staged (R16-proven) -------
__global__ void __launch_bounds__(1024)
k_part2(const int* __restrict__ srcA, const int* __restrict__ dstA,
        int* __restrict__ bcurA, unsigned int* __restrict__ outA, int EA, int nbA,
        const int* __restrict__ srcB, const int* __restrict__ dstB,
        int* __restrict__ bcurB, unsigned int* __restrict__ outB, int EB) {
    __shared__ int lh[1024];
    __shared__ int loff[1024];
    __shared__ int gof[1024];
    __shared__ int lcur[1024];
    __shared__ unsigned int stage[CHUNK];   // 64 KB
    const int *src, *dst; int *bcur; unsigned int *out; int E, cb;
    if ((int)blockIdx.x < nbA) { src = srcA; dst = dstA; bcur = bcurA; out = outA; E = EA; cb = blockIdx.x; }
    else                       { src = srcB; dst = dstB; bcur = bcurB; out = outB; E = EB; cb = blockIdx.x - nbA; }
    int t = threadIdx.x;
    int base = cb * CHUNK;
    int cnt = min(CHUNK, E - base);
    lh[t] = 0;
    __syncthreads();
    for (int i = t; i < cnt; i += 1024) atomicAdd(&lh[dst[base + i] >> 6], 1);
    __syncthreads();
    int vdeg = lh[t];
    int incl = vdeg;
    #pragma unroll
    for (int off = 1; off < 64; off <<= 1) {
        int tv = __shfl_up(incl, off);
        if ((t & 63) >= off) incl += tv;
    }
    if ((t & 63) == 63) gof[t >> 6] = incl;
    __syncthreads();
    if (t < 16) {
        int wv = gof[t];
        int winc = wv;
        #pragma unroll
        for (int off = 1; off < 16; off <<= 1) {
            int tv = __shfl_up(winc, off, 16);
            if (t >= off) winc += tv;
        }
        gof[16 + t] = winc - wv;
    }
    __syncthreads();
    int excl = incl - vdeg + gof[16 + (t >> 6)];
    loff[t] = excl;
    lcur[t] = excl;
    __syncthreads();
    gof[t] = vdeg ? atomicAdd(&bcur[t], vdeg) : 0;
    __syncthreads();
    for (int i = t; i < cnt; i += 1024) {
        int d = dst[base + i];
        int s = src[base + i];
        int bkt = d >> 6;
        int p = atomicAdd(&lcur[bkt], 1);
        stage[p] = (unsigned int)s | ((unsigned int)(d & 63) << 16) |
                   ((unsigned int)bkt << 22);
    }
    __syncthreads();
    for (int i = t; i < cnt; i += 1024) {
        unsigned int e = stage[i];
        int bkt = (int)(e >> 22);
        out[gof[bkt] + (i - loff[bkt])] = e & 0x3FFFFFu;
    }
}

// ------- fused CSR build: deg count + scan -> rs/dinv, then in-window scatter ----
__global__ void __launch_bounds__(256)
k_csr2(const int* __restrict__ bbaseA, const unsigned int* __restrict__ ebufA,
       int* __restrict__ rsA, float* __restrict__ dvA, unsigned short* __restrict__ ssrcA, int EA,
       const int* __restrict__ bbaseB, const unsigned int* __restrict__ ebufB,
       int* __restrict__ rsB, float* __restrict__ dvB, unsigned short* __restrict__ ssrcB, int EB,
       int B, int n) {
    __shared__ int cnt[64];
    __shared__ int lcur[64];
    const int* bbase; const unsigned int* ebuf; int* rs; float* dv;
    unsigned short* ssrc; int b, Etot;
    if ((int)blockIdx.x < B) { bbase = bbaseA; ebuf = ebufA; rs = rsA; dv = dvA; ssrc = ssrcA; b = blockIdx.x; Etot = EA; }
    else                     { bbase = bbaseB; ebuf = ebufB; rs = rsB; dv = dvB; ssrc = ssrcB; b = blockIdx.x - B; Etot = EB; }
    int t = threadIdx.x;
    if (t < 64) cnt[t] = 0;
    __syncthreads();
    int beg = bbase[b], end = bbase[b + 1];
    for (int i = beg + t; i < end; i += 256)
        atomicAdd(&cnt[(ebuf[i] >> 16) & 63u], 1);
    __syncthreads();
    if (t < 64) {
        int v = cnt[t];
        int incl = v;
        #pragma unroll
        for (int off = 1; off < 64; off <<= 1) {
            int tv = __shfl_up(incl, off);
            if (t >= off) incl += tv;
        }
        int start = beg + incl - v;
        lcur[t] = start;
        int node = b * NPB + t;
        if (node < n) {
            rs[node] = start;
            dv[node] = (v > 0) ? rsqrtf((float)v) : 0.f;
        }
    }
    __syncthreads();
    for (int i = beg + t; i < end; i += 256) {
        unsigned int e = ebuf[i];
        int p = atomicAdd(&lcur[(e >> 16) & 63u], 1);
        ssrc[p] = (unsigned short)(e & 0xFFFFu);
    }
    if (t == 0 && b == B - 1) rs[n] = Etot;
}

// ------- pack: psrc[i] = src | bf16(dinv[src])<<16 (both sets, grid-stride) ----
__global__ void k_pack(const unsigned short* __restrict__ ssrc1, const float* __restrict__ dinv1,
                       unsigned int* __restrict__ p1, int E1,
                       const unsigned short* __restrict__ ssrc2, const float* __restrict__ dinv2,
                       unsigned int* __restrict__ p2, int E2) {
    int stride = gridDim.x * 256;
    for (int i = blockIdx.x * 256 + threadIdx.x; i < E1 + E2; i += stride) {
        if (i < E1) {
            int s = ssrc1[i];
            p1[i] = (unsigned int)s | ((unsigned int)f2b(dinv1[s]) << 16);
        } else {
            int j = i - E1;
            int s = ssrc2[j];
            p2[j] = (unsigned int)s | ((unsigned int)f2b(dinv2[s]) << 16);
        }
    }
}

// ------- x8-unrolled 64-feat gather body; packed src+scale stream -------
__device__ inline void agg64_body(const int* __restrict__ rs,
                                  const unsigned int* __restrict__ psrc,
                                  const float* __restrict__ dinv,
                                  const us8* __restrict__ hwb8,
                                  const float* __restrict__ b1,
                                  unsigned short* __restrict__ R1b,
                                  int col_unit, int n, int tid) {
    int v = tid >> 3, q = tid & 7;
    if (v >= n) return;
    int beg = rs[v], end = rs[v + 1];
    float a[8] = {0.f, 0.f, 0.f, 0.f, 0.f, 0.f, 0.f, 0.f};
    int i = beg;
    for (; i + 8 <= end; i += 8) {
        unsigned int e0 = psrc[i + 0], e1 = psrc[i + 1], e2 = psrc[i + 2], e3 = psrc[i + 3];
        unsigned int e4 = psrc[i + 4], e5 = psrc[i + 5], e6 = psrc[i + 6], e7 = psrc[i + 7];
        int s0 = e0 & 0xFFFFu, s1 = e1 & 0xFFFFu, s2 = e2 & 0xFFFFu, s3 = e3 & 0xFFFFu;
        int s4 = e4 & 0xFFFFu, s5 = e5 & 0xFFFFu, s6 = e6 & 0xFFFFu, s7 = e7 & 0xFFFFu;
        float c0 = b2f((unsigned short)(e0 >> 16)), c1 = b2f((unsigned short)(e1 >> 16));
        float c2 = b2f((unsigned short)(e2 >> 16)), c3 = b2f((unsigned short)(e3 >> 16));
        float c4 = b2f((unsigned short)(e4 >> 16)), c5 = b2f((unsigned short)(e5 >> 16));
        float c6 = b2f((unsigned short)(e6 >> 16)), c7 = b2f((unsigned short)(e7 >> 16));
        us8 h0 = hwb8[s0 * 8 + q], h1 = hwb8[s1 * 8 + q];
        us8 h2 = hwb8[s2 * 8 + q], h3 = hwb8[s3 * 8 + q];
        us8 h4 = hwb8[s4 * 8 + q], h5 = hwb8[s5 * 8 + q];
        us8 h6 = hwb8[s6 * 8 + q], h7 = hwb8[s7 * 8 + q];
        #pragma unroll
        for (int j = 0; j < 8; ++j) {
            a[j] = fmaf(b2f(h0[j]), c0, a[j]);
            a[j] = fmaf(b2f(h1[j]), c1, a[j]);
            a[j] = fmaf(b2f(h2[j]), c2, a[j]);
            a[j] = fmaf(b2f(h3[j]), c3, a[j]);
            a[j] = fmaf(b2f(h4[j]), c4, a[j]);
            a[j] = fmaf(b2f(h5[j]), c5, a[j]);
            a[j] = fmaf(b2f(h6[j]), c6, a[j]);
            a[j] = fmaf(b2f(h7[j]), c7, a[j]);
        }
    }
    for (; i < end; ++i) {
        unsigned int e = psrc[i];
        int s = e & 0xFFFFu;
        float sc = b2f((unsigned short)(e >> 16));
        us8 h = hwb8[s * 8 + q];
        #pragma unroll
        for (int j = 0; j < 8; ++j) a[j] = fmaf(b2f(h[j]), sc, a[j]);
    }
    float dd = dinv[v];
    us8 o;
    #pragma unroll
    for (int j = 0; j < 8; ++j) {
        float r = fmaf(a[j], dd, b1[q * 8 + j]);
        o[j] = f2b(r > 0.f ? r : 0.f);
    }
    ((us8*)&R1b[v * 192])[col_unit + q] = o;
}

// ------- fused layer-1: E2 agg | E1 agg | self (blockIdx ranges; E2 first) -------
__global__ void k_agg1f(const int* __restrict__ rs1, const unsigned int* __restrict__ psrc1,
                        const float* __restrict__ dinv1,
                        const int* __restrict__ rs2, const unsigned int* __restrict__ psrc2,
                        const float* __restrict__ dinv2,
                        const us8* __restrict__ hwb8, const float* __restrict__ b1,
                        unsigned short* __restrict__ R1b, int n, int nba) {
    int bid = blockIdx.x;
    if (bid < nba) {
        agg64_body(rs2, psrc2, dinv2, hwb8, b1, R1b, 8, n, bid * 256 + threadIdx.x);
    } else if (bid < 2 * nba) {
        agg64_body(rs1, psrc1, dinv1, hwb8, b1, R1b, 0, n,
                   (bid - nba) * 256 + threadIdx.x);
    } else {
        int tid = (bid - 2 * nba) * 256 + threadIdx.x;
        int v = tid >> 3, q = tid & 7;
        if (v >= n) return;
        us8 h = hwb8[v * 8 + q];
        us8 o;
        #pragma unroll
        for (int j = 0; j < 8; ++j) {
            float r = b2f(h[j]) + b1[q * 8 + j];
            o[j] = f2b(r > 0.f ? r : 0.f);
        }
        ((us8*)&R1b[v * 192])[16 + q] = o;
    }
}

// ---------------- GEMM2: hwb2 = bf16(R1 @ w2)  ([n,192]@[192,16]) ----------------
__global__ void __launch_bounds__(256)
k_gemm2(const unsigned short* __restrict__ R1b, const float* __restrict__ w2,
        unsigned short* __restrict__ hwb2, int n) {
    __shared__ float ws[192 * 16];
    __shared__ float rs[16][193];
    int t = threadIdx.x;
    for (int i = t; i < 192 * 16; i += 256) ws[i] = w2[i];
    int row0 = blockIdx.x * 16;
    for (int i = t; i < 16 * 192; i += 256) {
        int r = i / 192, j = i - r * 192;
        int v = row0 + r;
        rs[r][j] = (v < n) ? b2f(R1b[v * 192 + j]) : 0.f;
    }
    __syncthreads();
    int r = t >> 4, c = t & 15;
    int v = row0 + r;
    if (v >= n) return;
    float acc = 0.f;
    #pragma unroll 8
    for (int j = 0; j < 192; ++j) acc += rs[r][j] * ws[j * 16 + c];
    hwb2[v * 16 + c] = f2b(acc);
}

// ------- 16-feat gather (2 lanes/node), packed stream, scalar loads -------
__device__ inline void gath16(const int* __restrict__ rs,
                              const unsigned int* __restrict__ psrc,
                              const us8* __restrict__ h8,
                              int v, int q, float* __restrict__ a) {
    int beg = rs[v], end = rs[v + 1];
    #pragma unroll
    for (int j = 0; j < 8; ++j) a[j] = 0.f;
    int i = beg;
    for (; i + 8 <= end; i += 8) {
        unsigned int e0 = psrc[i + 0], e1 = psrc[i + 1], e2 = psrc[i + 2], e3 = psrc[i + 3];
        unsigned int e4 = psrc[i + 4], e5 = psrc[i + 5], e6 = psrc[i + 6], e7 = psrc[i + 7];
        int s0 = e0 & 0xFFFFu, s1 = e1 & 0xFFFFu, s2 = e2 & 0xFFFFu, s3 = e3 & 0xFFFFu;
        int s4 = e4 & 0xFFFFu, s5 = e5 & 0xFFFFu, s6 = e6 & 0xFFFFu, s7 = e7 & 0xFFFFu;
        float c0 = b2f((unsigned short)(e0 >> 16)), c1 = b2f((unsigned short)(e1 >> 16));
        float c2 = b2f((unsigned short)(e2 >> 16)), c3 = b2f((unsigned short)(e3 >> 16));
        float c4 = b2f((unsigned short)(e4 >> 16)), c5 = b2f((unsigned short)(e5 >> 16));
        float c6 = b2f((unsigned short)(e6 >> 16)), c7 = b2f((unsigned short)(e7 >> 16));
        us8 h0 = h8[s0 * 2 + q], h1 = h8[s1 * 2 + q];
        us8 h2 = h8[s2 * 2 + q], h3 = h8[s3 * 2 + q];
        us8 h4 = h8[s4 * 2 + q], h5 = h8[s5 * 2 + q];
        us8 h6 = h8[s6 * 2 + q], h7 = h8[s7 * 2 + q];
        #pragma unroll
        for (int j = 0; j < 8; ++j) {
            a[j] = fmaf(b2f(h0[j]), c0, a[j]);
            a[j] = fmaf(b2f(h1[j]), c1, a[j]);
            a[j] = fmaf(b2f(h2[j]), c2, a[j]);
            a[j] = fmaf(b2f(h3[j]), c3, a[j]);
            a[j] = fmaf(b2f(h4[j]), c4, a[j]);
            a[j] = fmaf(b2f(h5[j]), c5, a[j]);
            a[j] = fmaf(b2f(h6[j]), c6, a[j]);
            a[j] = fmaf(b2f(h7[j]), c7, a[j]);
        }
    }
    for (; i < end; ++i) {
        unsigned int e = psrc[i];
        int s = e & 0xFFFFu;
        float sc = b2f((unsigned short)(e >> 16));
        us8 h = h8[s * 2 + q];
        #pragma unroll
        for (int j = 0; j < 8; ++j) a[j] = fmaf(b2f(h[j]), sc, a[j]);
    }
}

// ------- fused layer-2 aggregate + linear head + log_softmax (128 nodes/block) ----
__global__ void __launch_bounds__(256)
k_l2f(const int* __restrict__ rs1, const unsigned int* __restrict__ psrc1,
      const float* __restrict__ dinv1,
      const int* __restrict__ rs2, const unsigned int* __restrict__ psrc2,
      const float* __restrict__ dinv2,
      const us8* __restrict__ hwb2_8, const unsigned short* __restrict__ hwb2,
      const float* __restrict__ b2, const float* __restrict__ lw,
      const float* __restrict__ lb, float* __restrict__ out, int n) {
    __shared__ float accA[128 * 16];
    __shared__ float accB[128 * 16];
    __shared__ float lws[48 * 16];
    __shared__ float r2s[16][49];
    int t = threadIdx.x;
    int v0 = blockIdx.x * 128;
    for (int i = t; i < 48 * 16; i += 256) lws[i] = lw[i];
    int vl = t >> 1, q = t & 1;
    int v = v0 + vl;
    if (v < n) {
        float a[8];
        gath16(rs2, psrc2, hwb2_8, v, q, a);
        #pragma unroll
        for (int j = 0; j < 8; ++j) accB[vl * 16 + q * 8 + j] = a[j];
        gath16(rs1, psrc1, hwb2_8, v, q, a);
        #pragma unroll
        for (int j = 0; j < 8; ++j) accA[vl * 16 + q * 8 + j] = a[j];
    }
    __syncthreads();
    int ni = t >> 4, c = t & 15;
    for (int p = 0; p < 8; ++p) {
        int vv = v0 + p * 16 + ni;
        int vl2 = p * 16 + ni;
        if (vv < n) {
            float bb = b2[c];
            r2s[ni][c]      = fmaf(dinv1[vv], accA[vl2 * 16 + c], bb);
            r2s[ni][16 + c] = fmaf(dinv2[vv], accB[vl2 * 16 + c], bb);
            r2s[ni][32 + c] = b2f(hwb2[vv * 16 + c]) + bb;
        }
        __syncthreads();
        if (vv < n) {
            float o = lb[c];
            #pragma unroll
            for (int j = 0; j < 48; ++j) o += r2s[ni][j] * lws[j * 16 + c];
            float m = o;
            for (int off = 8; off >= 1; off >>= 1) m = fmaxf(m, __shfl_xor(m, off, 16));
            float e = expf(o - m);
            float ssum = e;
            for (int off = 8; off >= 1; off >>= 1) ssum += __shfl_xor(ssum, off, 16);
            out[vv * 16 + c] = (o - m) - logf(ssum);
        }
        __syncthreads();
    }
}

extern "C" void kernel_launch(void* const* d_in, const int* in_sizes, int n_in,
                              void* d_out, int out_size, void* d_ws, size_t ws_size,
                              hipStream_t stream) {
    const float* x     = (const float*)d_in[0];
    const float* w1    = (const float*)d_in[1];
    const float* b1    = (const float*)d_in[2];
    const float* w2    = (const float*)d_in[3];
    const float* b2    = (const float*)d_in[4];
    const float* lin_w = (const float*)d_in[5];
    const float* lin_b = (const float*)d_in[6];
    const int*   ei    = (const int*)d_in[7];
    const int*   ei2   = (const int*)d_in[8];

    const int n  = in_sizes[0] / 128;   // 50000
    const int E1 = in_sizes[7] / 2;     // 800000
    const int E2 = in_sizes[8] / 2;     // 3000000
    const int B  = (n + NPB - 1) / NPB; // 782

    char* ws = (char*)d_ws;
    unsigned short* hwb   = (unsigned short*)(ws + 0);         // [n,64] bf16 -> 6.4M
    unsigned short* hwb2  = (unsigned short*)(ws + 6400000);   // [n,16] bf16 -> 8.0M
    unsigned short* R1b   = (unsigned short*)(ws + 8000000);   // [n,192] bf16 -> 27.2M
    unsigned short* ssrc1 = (unsigned short*)(ws + 27200000);  // [E1] -> 28.8M
    unsigned short* ssrc2 = (unsigned short*)(ws + 28800000);  // [E2] -> 34.8M
    unsigned int* ebuf1   = (unsigned int*)(ws + 34800000);    // [E1] -> 38.0M (dead after csr2)
    unsigned int* ebuf2   = (unsigned int*)(ws + 38000000);    // [E2] -> 50.0M (dead after csr2)
    unsigned int* psrc1   = ebuf1;                             // packed reuse
    unsigned int* psrc2   = ebuf2;                             // packed reuse
    float*        dinv1   = (float*)(ws + 56800000);           // [n]
    float*        dinv2   = (float*)(ws + 57000000);           // [n]
    int*          rs1     = (int*)(ws + 57200000);             // [n+1]
    int*          rs2     = (int*)(ws + 57400016);             // [n+1]
    int*          bhist1  = (int*)(ws + 58000032);             // [1024]
    int*          bhist2  = (int*)(ws + 58004128);             // [1024] (contiguous)
    int*          bbase1  = (int*)(ws + 58008224);             // [B+1]
    int*          bbase2  = (int*)(ws + 58012320);             // [B+1]
    int*          bcur1   = (int*)(ws + 58016416);             // [1024]
    int*          bcur2   = (int*)(ws + 58020512);             // [1024]

    hipMemsetAsync(bhist1, 0, 8192, stream);   // bhist1+bhist2, contiguous

    k_gemm1<<<(n + 63) / 64, 256, 0, stream>>>(x, w1, hwb, n);

    const int nbh1 = (E1 + HCHUNK - 1) / HCHUNK, nbh2 = (E2 + HCHUNK - 1) / HCHUNK;
    k_hist2<<<nbh1 + nbh2, 256, 0, stream>>>(ei + E1, bhist1, E1, nbh1,
                                             ei2 + E2, bhist2, E2);
    k_bscan<<<2, 64, 0, stream>>>(bhist1, bbase1, bcur1, bhist2, bbase2, bcur2, B);

    const int nbp1 = (E1 + CHUNK - 1) / CHUNK, nbp2 = (E2 + CHUNK - 1) / CHUNK;
    k_part2<<<nbp1 + nbp2, 1024, 0, stream>>>(ei, ei + E1, bcur1, ebuf1, E1, nbp1,
                                              ei2, ei2 + E2, bcur2, ebuf2, E2);

    k_csr2<<<2 * B, 256, 0, stream>>>(bbase1, ebuf1, rs1, dinv1, ssrc1, E1,
                                      bbase2, ebuf2, rs2, dinv2, ssrc2, E2, B, n);

    k_pack<<<2048, 256, 0, stream>>>(ssrc1, dinv1, psrc1, E1, ssrc2, dinv2, psrc2, E2);

    const int nba = (n * 8 + 255) / 256;
    k_agg1f<<<3 * nba, 256, 0, stream>>>(rs1, psrc1, dinv1, rs2, psrc2, dinv2,
                                         (const us8*)hwb, b1, R1b, n, nba);

    k_gemm2<<<(n + 15) / 16, 256, 0, stream>>>(R1b, w2, hwb2, n);

    k_l2f<<<(n + 127) / 128, 256, 0, stream>>>(rs1, psrc1, dinv1, rs2, psrc2, dinv2,
                                               (const us8*)hwb2, hwb2, b2,
                                               lin_w, lin_b, (float*)d_out, n);
}

// Round 19
// 233.860 us; speedup vs baseline: 1.1359x; 1.0058x over previous
//
#include <hip/hip_runtime.h>
#include <math.h>

// x[50000,128] w1[128,64] b1[64] w2[192,16] b2[16] lin_w[48,16] lin_b[16]
// edge_index[2,800000] edge_index2[2,3000000] (int32, row0=src, row1=dst)
//
// R19 = R18 with the CSR scatter fused with the psrc pack: k_csr2a (count+
// scan -> rs/dinv) + k_csr2b (windowed scatter writing psrc = src|bf16(dinv
// [src])<<16 directly, R8-proven cursor pattern). Deletes k_pack and the
// ssrc relay buffer (one fewer dispatch, ~15MB less traffic). psrc now has
// its own region (no ebuf aliasing; csr2b reads ebuf while writing psrc).

#define NPB    64
#define CHUNK  16384
#define HCHUNK 16384

typedef unsigned short us8 __attribute__((ext_vector_type(8)));

__device__ inline float b2f(unsigned short u) {
    return __uint_as_float(((unsigned int)u) << 16);
}
// round-to-nearest-even f32 -> bf16 (finite values; matches __float2bfloat16)
__device__ inline unsigned short f2b(float f) {
    unsigned int u = __float_as_uint(f);
    u = (u + 0x7FFFu + ((u >> 16) & 1u)) >> 16;
    return (unsigned short)u;
}

// ---- GEMM1: hwb = bf16(x @ w1), 64 rows/block, 4x4 tile/thread ----
__global__ void __launch_bounds__(256)
k_gemm1(const float* __restrict__ x, const float* __restrict__ w1,
        unsigned short* __restrict__ hwb, int n) {
    __shared__ float ws[128 * 64];   // 32 KB, [k][c]
    __shared__ float xs[64 * 128];   // 32 KB, [r][k]
    int t = threadIdx.x;
    int row0 = blockIdx.x * 64;
    for (int i = t; i < 128 * 16; i += 256)
        ((float4*)ws)[i] = ((const float4*)w1)[i];
    for (int i = t; i < 64 * 32; i += 256) {
        int r = row0 + (i >> 5);
        ((float4*)xs)[i] = (r < n) ? ((const float4*)x)[r * 32 + (i & 31)]
                                   : make_float4(0.f, 0.f, 0.f, 0.f);
    }
    __syncthreads();
    int tr = t >> 4, tc = t & 15;
    float acc[4][4] = {};
    #pragma unroll 4
    for (int k4 = 0; k4 < 32; ++k4) {
        float4 wv0 = *(const float4*)&ws[(k4 * 4 + 0) * 64 + tc * 4];
        float4 wv1 = *(const float4*)&ws[(k4 * 4 + 1) * 64 + tc * 4];
        float4 wv2 = *(const float4*)&ws[(k4 * 4 + 2) * 64 + tc * 4];
        float4 wv3 = *(const float4*)&ws[(k4 * 4 + 3) * 64 + tc * 4];
        #pragma unroll
        for (int r = 0; r < 4; ++r) {
            float4 xv = *(const float4*)&xs[(tr * 4 + r) * 128 + k4 * 4];
            acc[r][0] = fmaf(xv.x, wv0.x, acc[r][0]);
            acc[r][1] = fmaf(xv.x, wv0.y, acc[r][1]);
            acc[r][2] = fmaf(xv.x, wv0.z, acc[r][2]);
            acc[r][3] = fmaf(xv.x, wv0.w, acc[r][3]);
            acc[r][0] = fmaf(xv.y, wv1.x, acc[r][0]);
            acc[r][1] = fmaf(xv.y, wv1.y, acc[r][1]);
            acc[r][2] = fmaf(xv.y, wv1.z, acc[r][2]);
            acc[r][3] = fmaf(xv.y, wv1.w, acc[r][3]);
            acc[r][0] = fmaf(xv.z, wv2.x, acc[r][0]);
            acc[r][1] = fmaf(xv.z, wv2.y, acc[r][1]);
            acc[r][2] = fmaf(xv.z, wv2.z, acc[r][2]);
            acc[r][3] = fmaf(xv.z, wv2.w, acc[r][3]);
            acc[r][0] = fmaf(xv.w, wv3.x, acc[r][0]);
            acc[r][1] = fmaf(xv.w, wv3.y, acc[r][1]);
            acc[r][2] = fmaf(xv.w, wv3.z, acc[r][2]);
            acc[r][3] = fmaf(xv.w, wv3.w, acc[r][3]);
        }
    }
    #pragma unroll
    for (int r = 0; r < 4; ++r) {
        int rr = row0 + tr * 4 + r;
        if (rr < n) {
            ushort4 o;
            o.x = f2b(acc[r][0]); o.y = f2b(acc[r][1]);
            o.z = f2b(acc[r][2]); o.w = f2b(acc[r][3]);
            *(ushort4*)&hwb[rr * 64 + tc * 4] = o;
        }
    }
}

// ------- fused bucket histogram, both edge sets; int4-vectorized dst reads -------
__global__ void k_hist2(const int* __restrict__ dstA, int* __restrict__ bhA, int EA, int nbA,
                        const int* __restrict__ dstB, int* __restrict__ bhB, int EB) {
    __shared__ int lh[1024];
    const int* dst; int* bh; int E; int cb;
    if ((int)blockIdx.x < nbA) { dst = dstA; bh = bhA; E = EA; cb = blockIdx.x; }
    else                       { dst = dstB; bh = bhB; E = EB; cb = blockIdx.x - nbA; }
    int t = threadIdx.x;
    for (int i = t; i < 1024; i += 256) lh[i] = 0;
    __syncthreads();
    int base = cb * HCHUNK;
    int cnt = min(HCHUNK, E - base);
    int nv = cnt >> 2;
    const int4* d4 = (const int4*)(dst + base);   // base & ptr both 16B-aligned
    for (int i = t; i < nv; i += 256) {
        int4 d = d4[i];
        atomicAdd(&lh[d.x >> 6], 1);
        atomicAdd(&lh[d.y >> 6], 1);
        atomicAdd(&lh[d.z >> 6], 1);
        atomicAdd(&lh[d.w >> 6], 1);
    }
    for (int i = (nv << 2) + t; i < cnt; i += 256)
        atomicAdd(&lh[dst[base + i] >> 6], 1);
    __syncthreads();
    for (int b = t; b < 1024; b += 256)
        if (lh[b]) atomicAdd(&bh[b], lh[b]);
}

// ------- scan bucket histograms -> bbase (exclusive) and bcur -------
__global__ void k_bscan(const int* __restrict__ bhA, int* __restrict__ bbA, int* __restrict__ bcA,
                        const int* __restrict__ bhB, int* __restrict__ bbB, int* __restrict__ bcB,
                        int B) {
    const int* bh = blockIdx.x ? bhB : bhA;
    int* bb = blockIdx.x ? bbB : bbA;
    int* bc = blockIdx.x ? bcB : bcA;
    int t = threadIdx.x;
    int carry = 0;
    int nch = (B + 63) >> 6;
    for (int c = 0; c < nch; ++c) {
        int idx = c * 64 + t;
        int v = (idx < B) ? bh[idx] : 0;
        int incl = v;
        #pragma unroll
        for (int off = 1; off < 64; off <<= 1) {
            int tv = __shfl_up(incl, off);
            if (t >= off) incl += tv;
        }
        if (idx < B) { bb[idx] = incl - v + carry; bc[idx] = incl - v + carry; }
        carry += __shfl(incl, 63);
    }
    if (t == 0) bb[B] = carry;
}

// ------- fused coarse partition, 1024 threads, staged (R16-proven) -------
__global__ void __launch_bounds__(1024)
k_part2(const int* __restrict__ srcA, const int* __restrict__ dstA,
        int* __restrict__ bcurA, unsigned int* __restrict__ outA, int EA, int nbA,
        const int* __restrict__ srcB, const int* __restrict__ dstB,
        int* __restrict__ bcurB, unsigned int* __restrict__ outB, int EB) {
    __shared__ int lh[1024];
    __shared__ int loff[1024];
    __shared__ int gof[1024];
    __shared__ int lcur[1024];
    __shared__ unsigned int stage[CHUNK];   // 64 KB
    const int *src, *dst; int *bcur; unsigned int *out; int E, cb;
    if ((int)blockIdx.x < nbA) { src = srcA; dst = dstA; bcur = bcurA; out = outA; E = EA; cb = blockIdx.x; }
    else                       { src = srcB; dst = dstB; bcur = bcurB; out = outB; E = EB; cb = blockIdx.x - nbA; }
    int t = threadIdx.x;
    int base = cb * CHUNK;
    int cnt = min(CHUNK, E - base);
    lh[t] = 0;
    __syncthreads();
    for (int i = t; i < cnt; i += 1024) atomicAdd(&lh[dst[base + i] >> 6], 1);
    __syncthreads();
    int vdeg = lh[t];
    int incl = vdeg;
    #pragma unroll
    for (int off = 1; off < 64; off <<= 1) {
        int tv = __shfl_up(incl, off);
        if ((t & 63) >= off) incl += tv;
    }
    if ((t & 63) == 63) gof[t >> 6] = incl;
    __syncthreads();
    if (t < 16) {
        int wv = gof[t];
        int winc = wv;
        #pragma unroll
        for (int off = 1; off < 16; off <<= 1) {
            int tv = __shfl_up(winc, off, 16);
            if (t >= off) winc += tv;
        }
        gof[16 + t] = winc - wv;
    }
    __syncthreads();
    int excl = incl - vdeg + gof[16 + (t >> 6)];
    loff[t] = excl;
    lcur[t] = excl;
    __syncthreads();
    gof[t] = vdeg ? atomicAdd(&bcur[t], vdeg) : 0;
    __syncthreads();
    for (int i = t; i < cnt; i += 1024) {
        int d = dst[base + i];
        int s = src[base + i];
        int bkt = d >> 6;
        int p = atomicAdd(&lcur[bkt], 1);
        stage[p] = (unsigned int)s | ((unsigned int)(d & 63) << 16) |
                   ((unsigned int)bkt << 22);
    }
    __syncthreads();
    for (int i = t; i < cnt; i += 1024) {
        unsigned int e = stage[i];
        int bkt = (int)(e >> 22);
        out[gof[bkt] + (i - loff[bkt])] = e & 0x3FFFFFu;
    }
}

// ------- CSR phase A: per-bucket deg count + scan -> rs, dinv -------
__global__ void __launch_bounds__(256)
k_csr2a(const int* __restrict__ bbaseA, const unsigned int* __restrict__ ebufA,
        int* __restrict__ rsA, float* __restrict__ dvA, int EA,
        const int* __restrict__ bbaseB, const unsigned int* __restrict__ ebufB,
        int* __restrict__ rsB, float* __restrict__ dvB, int EB, int B, int n) {
    __shared__ int cnt[64];
    const int* bbase; const unsigned int* ebuf; int* rs; float* dv; int b, Etot;
    if ((int)blockIdx.x < B) { bbase = bbaseA; ebuf = ebufA; rs = rsA; dv = dvA; b = blockIdx.x; Etot = EA; }
    else                     { bbase = bbaseB; ebuf = ebufB; rs = rsB; dv = dvB; b = blockIdx.x - B; Etot = EB; }
    int t = threadIdx.x;
    if (t < 64) cnt[t] = 0;
    __syncthreads();
    int beg = bbase[b], end = bbase[b + 1];
    for (int i = beg + t; i < end; i += 256)
        atomicAdd(&cnt[(ebuf[i] >> 16) & 63u], 1);
    __syncthreads();
    if (t < 64) {
        int v = cnt[t];
        int incl = v;
        #pragma unroll
        for (int off = 1; off < 64; off <<= 1) {
            int tv = __shfl_up(incl, off);
            if (t >= off) incl += tv;
        }
        int node = b * NPB + t;
        if (node < n) {
            rs[node] = beg + incl - v;
            dv[node] = (v > 0) ? rsqrtf((float)v) : 0.f;
        }
    }
    if (t == 0 && b == B - 1) rs[n] = Etot;
}

// ------- CSR phase B: windowed scatter fused with pack -------
// psrc[p] = src | bf16(dinv[src])<<16 ; cursors seeded from global rs.
__global__ void __launch_bounds__(256)
k_csr2b(const int* __restrict__ bbaseA, const unsigned int* __restrict__ ebufA,
        const int* __restrict__ rsA, const float* __restrict__ dvA,
        unsigned int* __restrict__ psrcA,
        const int* __restrict__ bbaseB, const unsigned int* __restrict__ ebufB,
        const int* __restrict__ rsB, const float* __restrict__ dvB,
        unsigned int* __restrict__ psrcB, int B, int n) {
    __shared__ int lcur[64];
    const int *bbase, *rs; const unsigned int* ebuf; const float* dv;
    unsigned int* psrc; int b;
    if ((int)blockIdx.x < B) { bbase = bbaseA; ebuf = ebufA; rs = rsA; dv = dvA; psrc = psrcA; b = blockIdx.x; }
    else                     { bbase = bbaseB; ebuf = ebufB; rs = rsB; dv = dvB; psrc = psrcB; b = blockIdx.x - B; }
    int t = threadIdx.x;
    if (t < 64) {
        int node = b * NPB + t;
        lcur[t] = (node < n) ? rs[node] : 0;
    }
    __syncthreads();
    int beg = bbase[b], end = bbase[b + 1];
    for (int i = beg + t; i < end; i += 256) {
        unsigned int e = ebuf[i];
        int s = (int)(e & 0xFFFFu);
        int p = atomicAdd(&lcur[(e >> 16) & 63u], 1);
        psrc[p] = (unsigned int)s | ((unsigned int)f2b(dv[s]) << 16);
    }
}

// ------- x8-unrolled 64-feat gather body; packed src+scale stream -------
__device__ inline void agg64_body(const int* __restrict__ rs,
                                  const unsigned int* __restrict__ psrc,
                                  const float* __restrict__ dinv,
                                  const us8* __restrict__ hwb8,
                                  const float* __restrict__ b1,
                                  unsigned short* __restrict__ R1b,
                                  int col_unit, int n, int tid) {
    int v = tid >> 3, q = tid & 7;
    if (v >= n) return;
    int beg = rs[v], end = rs[v + 1];
    float a[8] = {0.f, 0.f, 0.f, 0.f, 0.f, 0.f, 0.f, 0.f};
    int i = beg;
    for (; i + 8 <= end; i += 8) {
        unsigned int e0 = psrc[i + 0], e1 = psrc[i + 1], e2 = psrc[i + 2], e3 = psrc[i + 3];
        unsigned int e4 = psrc[i + 4], e5 = psrc[i + 5], e6 = psrc[i + 6], e7 = psrc[i + 7];
        int s0 = e0 & 0xFFFFu, s1 = e1 & 0xFFFFu, s2 = e2 & 0xFFFFu, s3 = e3 & 0xFFFFu;
        int s4 = e4 & 0xFFFFu, s5 = e5 & 0xFFFFu, s6 = e6 & 0xFFFFu, s7 = e7 & 0xFFFFu;
        float c0 = b2f((unsigned short)(e0 >> 16)), c1 = b2f((unsigned short)(e1 >> 16));
        float c2 = b2f((unsigned short)(e2 >> 16)), c3 = b2f((unsigned short)(e3 >> 16));
        float c4 = b2f((unsigned short)(e4 >> 16)), c5 = b2f((unsigned short)(e5 >> 16));
        float c6 = b2f((unsigned short)(e6 >> 16)), c7 = b2f((unsigned short)(e7 >> 16));
        us8 h0 = hwb8[s0 * 8 + q], h1 = hwb8[s1 * 8 + q];
        us8 h2 = hwb8[s2 * 8 + q], h3 = hwb8[s3 * 8 + q];
        us8 h4 = hwb8[s4 * 8 + q], h5 = hwb8[s5 * 8 + q];
        us8 h6 = hwb8[s6 * 8 + q], h7 = hwb8[s7 * 8 + q];
        #pragma unroll
        for (int j = 0; j < 8; ++j) {
            a[j] = fmaf(b2f(h0[j]), c0, a[j]);
            a[j] = fmaf(b2f(h1[j]), c1, a[j]);
            a[j] = fmaf(b2f(h2[j]), c2, a[j]);
            a[j] = fmaf(b2f(h3[j]), c3, a[j]);
            a[j] = fmaf(b2f(h4[j]), c4, a[j]);
            a[j] = fmaf(b2f(h5[j]), c5, a[j]);
            a[j] = fmaf(b2f(h6[j]), c6, a[j]);
            a[j] = fmaf(b2f(h7[j]), c7, a[j]);
        }
    }
    for (; i < end; ++i) {
        unsigned int e = psrc[i];
        int s = e & 0xFFFFu;
        float sc = b2f((unsigned short)(e >> 16));
        us8 h = hwb8[s * 8 + q];
        #pragma unroll
        for (int j = 0; j < 8; ++j) a[j] = fmaf(b2f(h[j]), sc, a[j]);
    }
    float dd = dinv[v];
    us8 o;
    #pragma unroll
    for (int j = 0; j < 8; ++j) {
        float r = fmaf(a[j], dd, b1[q * 8 + j]);
        o[j] = f2b(r > 0.f ? r : 0.f);
    }
    ((us8*)&R1b[v * 192])[col_unit + q] = o;
}

// ------- fused layer-1: E2 agg | E1 agg | self (blockIdx ranges; E2 first) -------
__global__ void k_agg1f(const int* __restrict__ rs1, const unsigned int* __restrict__ psrc1,
                        const float* __restrict__ dinv1,
                        const int* __restrict__ rs2, const unsigned int* __restrict__ psrc2,
                        const float* __restrict__ dinv2,
                        const us8* __restrict__ hwb8, const float* __restrict__ b1,
                        unsigned short* __restrict__ R1b, int n, int nba) {
    int bid = blockIdx.x;
    if (bid < nba) {
        agg64_body(rs2, psrc2, dinv2, hwb8, b1, R1b, 8, n, bid * 256 + threadIdx.x);
    } else if (bid < 2 * nba) {
        agg64_body(rs1, psrc1, dinv1, hwb8, b1, R1b, 0, n,
                   (bid - nba) * 256 + threadIdx.x);
    } else {
        int tid = (bid - 2 * nba) * 256 + threadIdx.x;
        int v = tid >> 3, q = tid & 7;
        if (v >= n) return;
        us8 h = hwb8[v * 8 + q];
        us8 o;
        #pragma unroll
        for (int j = 0; j < 8; ++j) {
            float r = b2f(h[j]) + b1[q * 8 + j];
            o[j] = f2b(r > 0.f ? r : 0.f);
        }
        ((us8*)&R1b[v * 192])[16 + q] = o;
    }
}

// ---------------- GEMM2: hwb2 = bf16(R1 @ w2)  ([n,192]@[192,16]) ----------------
__global__ void __launch_bounds__(256)
k_gemm2(const unsigned short* __restrict__ R1b, const float* __restrict__ w2,
        unsigned short* __restrict__ hwb2, int n) {
    __shared__ float ws[192 * 16];
    __shared__ float rs[16][193];
    int t = threadIdx.x;
    for (int i = t; i < 192 * 16; i += 256) ws[i] = w2[i];
    int row0 = blockIdx.x * 16;
    for (int i = t; i < 16 * 192; i += 256) {
        int r = i / 192, j = i - r * 192;
        int v = row0 + r;
        rs[r][j] = (v < n) ? b2f(R1b[v * 192 + j]) : 0.f;
    }
    __syncthreads();
    int r = t >> 4, c = t & 15;
    int v = row0 + r;
    if (v >= n) return;
    float acc = 0.f;
    #pragma unroll 8
    for (int j = 0; j < 192; ++j) acc += rs[r][j] * ws[j * 16 + c];
    hwb2[v * 16 + c] = f2b(acc);
}

// ------- 16-feat gather (2 lanes/node), packed stream, scalar loads -------
__device__ inline void gath16(const int* __restrict__ rs,
                              const unsigned int* __restrict__ psrc,
                              const us8* __restrict__ h8,
                              int v, int q, float* __restrict__ a) {
    int beg = rs[v], end = rs[v + 1];
    #pragma unroll
    for (int j = 0; j < 8; ++j) a[j] = 0.f;
    int i = beg;
    for (; i + 8 <= end; i += 8) {
        unsigned int e0 = psrc[i + 0], e1 = psrc[i + 1], e2 = psrc[i + 2], e3 = psrc[i + 3];
        unsigned int e4 = psrc[i + 4], e5 = psrc[i + 5], e6 = psrc[i + 6], e7 = psrc[i + 7];
        int s0 = e0 & 0xFFFFu, s1 = e1 & 0xFFFFu, s2 = e2 & 0xFFFFu, s3 = e3 & 0xFFFFu;
        int s4 = e4 & 0xFFFFu, s5 = e5 & 0xFFFFu, s6 = e6 & 0xFFFFu, s7 = e7 & 0xFFFFu;
        float c0 = b2f((unsigned short)(e0 >> 16)), c1 = b2f((unsigned short)(e1 >> 16));
        float c2 = b2f((unsigned short)(e2 >> 16)), c3 = b2f((unsigned short)(e3 >> 16));
        float c4 = b2f((unsigned short)(e4 >> 16)), c5 = b2f((unsigned short)(e5 >> 16));
        float c6 = b2f((unsigned short)(e6 >> 16)), c7 = b2f((unsigned short)(e7 >> 16));
        us8 h0 = h8[s0 * 2 + q], h1 = h8[s1 * 2 + q];
        us8 h2 = h8[s2 * 2 + q], h3 = h8[s3 * 2 + q];
        us8 h4 = h8[s4 * 2 + q], h5 = h8[s5 * 2 + q];
        us8 h6 = h8[s6 * 2 + q], h7 = h8[s7 * 2 + q];
        #pragma unroll
        for (int j = 0; j < 8; ++j) {
            a[j] = fmaf(b2f(h0[j]), c0, a[j]);
            a[j] = fmaf(b2f(h1[j]), c1, a[j]);
            a[j] = fmaf(b2f(h2[j]), c2, a[j]);
            a[j] = fmaf(b2f(h3[j]), c3, a[j]);
            a[j] = fmaf(b2f(h4[j]), c4, a[j]);
            a[j] = fmaf(b2f(h5[j]), c5, a[j]);
            a[j] = fmaf(b2f(h6[j]), c6, a[j]);
            a[j] = fmaf(b2f(h7[j]), c7, a[j]);
        }
    }
    for (; i < end; ++i) {
        unsigned int e = psrc[i];
        int s = e & 0xFFFFu;
        float sc = b2f((unsigned short)(e >> 16));
        us8 h = h8[s * 2 + q];
        #pragma unroll
        for (int j = 0; j < 8; ++j) a[j] = fmaf(b2f(h[j]), sc, a[j]);
    }
}

// ------- fused layer-2 aggregate + linear head + log_softmax (128 nodes/block) ----
__global__ void __launch_bounds__(256)
k_l2f(const int* __restrict__ rs1, const unsigned int* __restrict__ psrc1,
      const float* __restrict__ dinv1,
      const int* __restrict__ rs2, const unsigned int* __restrict__ psrc2,
      const float* __restrict__ dinv2,
      const us8* __restrict__ hwb2_8, const unsigned short* __restrict__ hwb2,
      const float* __restrict__ b2, const float* __restrict__ lw,
      const float* __restrict__ lb, float* __restrict__ out, int n) {
    __shared__ float accA[128 * 16];
    __shared__ float accB[128 * 16];
    __shared__ float lws[48 * 16];
    __shared__ float r2s[16][49];
    int t = threadIdx.x;
    int v0 = blockIdx.x * 128;
    for (int i = t; i < 48 * 16; i += 256) lws[i] = lw[i];
    int vl = t >> 1, q = t & 1;
    int v = v0 + vl;
    if (v < n) {
        float a[8];
        gath16(rs2, psrc2, hwb2_8, v, q, a);
        #pragma unroll
        for (int j = 0; j < 8; ++j) accB[vl * 16 + q * 8 + j] = a[j];
        gath16(rs1, psrc1, hwb2_8, v, q, a);
        #pragma unroll
        for (int j = 0; j < 8; ++j) accA[vl * 16 + q * 8 + j] = a[j];
    }
    __syncthreads();
    int ni = t >> 4, c = t & 15;
    for (int p = 0; p < 8; ++p) {
        int vv = v0 + p * 16 + ni;
        int vl2 = p * 16 + ni;
        if (vv < n) {
            float bb = b2[c];
            r2s[ni][c]      = fmaf(dinv1[vv], accA[vl2 * 16 + c], bb);
            r2s[ni][16 + c] = fmaf(dinv2[vv], accB[vl2 * 16 + c], bb);
            r2s[ni][32 + c] = b2f(hwb2[vv * 16 + c]) + bb;
        }
        __syncthreads();
        if (vv < n) {
            float o = lb[c];
            #pragma unroll
            for (int j = 0; j < 48; ++j) o += r2s[ni][j] * lws[j * 16 + c];
            float m = o;
            for (int off = 8; off >= 1; off >>= 1) m = fmaxf(m, __shfl_xor(m, off, 16));
            float e = expf(o - m);
            float ssum = e;
            for (int off = 8; off >= 1; off >>= 1) ssum += __shfl_xor(ssum, off, 16);
            out[vv * 16 + c] = (o - m) - logf(ssum);
        }
        __syncthreads();
    }
}

extern "C" void kernel_launch(void* const* d_in, const int* in_sizes, int n_in,
                              void* d_out, int out_size, void* d_ws, size_t ws_size,
                              hipStream_t stream) {
    const float* x     = (const float*)d_in[0];
    const float* w1    = (const float*)d_in[1];
    const float* b1    = (const float*)d_in[2];
    const float* w2    = (const float*)d_in[3];
    const float* b2    = (const float*)d_in[4];
    const float* lin_w = (const float*)d_in[5];
    const float* lin_b = (const float*)d_in[6];
    const int*   ei    = (const int*)d_in[7];
    const int*   ei2   = (const int*)d_in[8];

    const int n  = in_sizes[0] / 128;   // 50000
    const int E1 = in_sizes[7] / 2;     // 800000
    const int E2 = in_sizes[8] / 2;     // 3000000
    const int B  = (n + NPB - 1) / NPB; // 782

    char* ws = (char*)d_ws;
    unsigned short* hwb   = (unsigned short*)(ws + 0);         // [n,64] bf16 -> 6.4M
    unsigned short* hwb2  = (unsigned short*)(ws + 6400000);   // [n,16] bf16 -> 8.0M
    unsigned short* R1b   = (unsigned short*)(ws + 8000000);   // [n,192] bf16 -> 27.2M
    unsigned int* psrc1   = (unsigned int*)(ws + 27200000);    // [E1] uint -> 30.4M
    unsigned int* psrc2   = (unsigned int*)(ws + 30400000);    // [E2] uint -> 42.4M
    unsigned int* ebuf1   = (unsigned int*)(ws + 42400000);    // [E1] -> 45.6M
    unsigned int* ebuf2   = (unsigned int*)(ws + 45600000);    // [E2] -> 57.6M
    float*        dinv1   = (float*)(ws + 57600000);           // [n]
    float*        dinv2   = (float*)(ws + 57800000);           // [n]
    int*          rs1     = (int*)(ws + 58000000);             // [n+1]
    int*          rs2     = (int*)(ws + 58200016);             // [n+1]
    int*          bhist1  = (int*)(ws + 58400032);             // [1024]
    int*          bhist2  = (int*)(ws + 58404128);             // [1024] (contiguous)
    int*          bbase1  = (int*)(ws + 58408224);             // [B+1]
    int*          bbase2  = (int*)(ws + 58412320);             // [B+1]
    int*          bcur1   = (int*)(ws + 58416416);             // [1024]
    int*          bcur2   = (int*)(ws + 58420512);             // [1024]

    hipMemsetAsync(bhist1, 0, 8192, stream);   // bhist1+bhist2, contiguous

    k_gemm1<<<(n + 63) / 64, 256, 0, stream>>>(x, w1, hwb, n);

    const int nbh1 = (E1 + HCHUNK - 1) / HCHUNK, nbh2 = (E2 + HCHUNK - 1) / HCHUNK;
    k_hist2<<<nbh1 + nbh2, 256, 0, stream>>>(ei + E1, bhist1, E1, nbh1,
                                             ei2 + E2, bhist2, E2);
    k_bscan<<<2, 64, 0, stream>>>(bhist1, bbase1, bcur1, bhist2, bbase2, bcur2, B);

    const int nbp1 = (E1 + CHUNK - 1) / CHUNK, nbp2 = (E2 + CHUNK - 1) / CHUNK;
    k_part2<<<nbp1 + nbp2, 1024, 0, stream>>>(ei, ei + E1, bcur1, ebuf1, E1, nbp1,
                                              ei2, ei2 + E2, bcur2, ebuf2, E2);

    k_csr2a<<<2 * B, 256, 0, stream>>>(bbase1, ebuf1, rs1, dinv1, E1,
                                       bbase2, ebuf2, rs2, dinv2, E2, B, n);
    k_csr2b<<<2 * B, 256, 0, stream>>>(bbase1, ebuf1, rs1, dinv1, psrc1,
                                       bbase2, ebuf2, rs2, dinv2, psrc2, B, n);

    const int nba = (n * 8 + 255) / 256;
    k_agg1f<<<3 * nba, 256, 0, stream>>>(rs1, psrc1, dinv1, rs2, psrc2, dinv2,
                                         (const us8*)hwb, b1, R1b, n, nba);

    k_gemm2<<<(n + 15) / 16, 256, 0, stream>>>(R1b, w2, hwb2, n);

    k_l2f<<<(n + 127) / 128, 256, 0, stream>>>(rs1, psrc1, dinv1, rs2, psrc2, dinv2,
                                               (const us8*)hwb2, hwb2, b2,
                                               lin_w, lin_b, (float*)d_out, n);
}